// Round 1
// baseline (1056.002 us; speedup 1.0000x reference)
//
#include <hip/hip_runtime.h>

// ALSH masked linear: out[B,N] = x @ (W * mask)^T, mask from bucket match.
// B=2048, D=2048, N=32768, M_AUG=5, TABLE=64, R=4.0, U=0.83.

#define D_DIM 2048
#define N_ROWS 32768
#define B_ROWS 2048
#define M_AUG_C 5
#define TBL 64
#define RBIN 4.0
#define USC 0.83

typedef short bf16x8 __attribute__((ext_vector_type(8)));
typedef float f32x4 __attribute__((ext_vector_type(4)));

// ---- workspace layout (bytes). Total ~0.9 MB. ----
#define WS_ROWSUMSQ 0                                  // double[N]
#define WS_ROWDOTA  (WS_ROWSUMSQ + N_ROWS * 8)         // double[N]
#define WS_PARTIAL  (WS_ROWDOTA + N_ROWS * 8)          // double[16*D]
#define WS_MAXSS    (WS_PARTIAL + 16 * D_DIM * 8)      // double
#define WS_QBUCKET  (WS_MAXSS + 8)                     // int
#define WS_COUNT    (WS_QBUCKET + 4)                   // int
#define WS_LIST     (WS_COUNT + 4)                     // int[N]

__device__ __forceinline__ unsigned short f2bf(float f) {
    unsigned int u = __builtin_bit_cast(unsigned int, f);
    u += 0x7fffu + ((u >> 16) & 1u);   // round-to-nearest-even
    return (unsigned short)(u >> 16);
}

// ---- Kernel A: per-row sum(W^2) and dot(W_row, a[:D]), fp64. One wave/row. ----
__global__ void rowstats_kernel(const float* __restrict__ W,
                                const float* __restrict__ a,
                                double* __restrict__ rowSumSq,
                                double* __restrict__ rowDotA) {
    int wave = threadIdx.x >> 6;
    int lane = threadIdx.x & 63;
    int row  = blockIdx.x * 4 + wave;
    const float* wr = W + (size_t)row * D_DIM;
    double ss = 0.0, da = 0.0;
#pragma unroll
    for (int c = 0; c < 8; ++c) {
        int off = c * 256 + lane * 4;
        float4 v  = *(const float4*)(wr + off);
        float4 av = *(const float4*)(a + off);
        ss += (double)v.x * v.x + (double)v.y * v.y + (double)v.z * v.z + (double)v.w * v.w;
        da += (double)v.x * av.x + (double)v.y * av.y + (double)v.z * av.z + (double)v.w * av.w;
    }
    for (int off = 32; off > 0; off >>= 1) {
        ss += __shfl_down(ss, off);
        da += __shfl_down(da, off);
    }
    if (lane == 0) { rowSumSq[row] = ss; rowDotA[row] = da; }
}

// ---- Kernel B: max over rowSumSq ----
__global__ void maxred_kernel(const double* __restrict__ rowSumSq,
                              double* __restrict__ maxOut) {
    __shared__ double sm[1024];
    double m = 0.0;
    for (int i = threadIdx.x; i < N_ROWS; i += 1024) m = fmax(m, rowSumSq[i]);
    sm[threadIdx.x] = m;
    __syncthreads();
    for (int s = 512; s > 0; s >>= 1) {
        if (threadIdx.x < s) sm[threadIdx.x] = fmax(sm[threadIdx.x], sm[threadIdx.x + s]);
        __syncthreads();
    }
    if (threadIdx.x == 0) *maxOut = sm[0];
}

// ---- Kernel C1: partial column sums of x (16 chunks of 128 rows) ----
__global__ void colsum_kernel(const float* __restrict__ x,
                              double* __restrict__ partial) {
    int col   = blockIdx.x * 256 + threadIdx.x;
    int chunk = blockIdx.y;
    const float* xp = x + (size_t)chunk * 128 * D_DIM + col;
    double s = 0.0;
#pragma unroll 8
    for (int b = 0; b < 128; ++b) s += (double)xp[(size_t)b * D_DIM];
    partial[(size_t)chunk * D_DIM + col] = s;
}

// ---- Kernel C2: finish column sums, compute query bucket ----
__global__ void qhash_kernel(const double* __restrict__ partial,
                             const float* __restrict__ a,
                             int* __restrict__ qBucket) {
    __shared__ double s_ssq[256], s_dta[256];
    int tid = threadIdx.x;
    double ssq = 0.0, dta = 0.0;
    for (int c = tid; c < D_DIM; c += 256) {
        double cs = 0.0;
#pragma unroll
        for (int k = 0; k < 16; ++k) cs += partial[(size_t)k * D_DIM + c];
        ssq += cs * cs;
        dta += cs * (double)a[c];
    }
    s_ssq[tid] = ssq; s_dta[tid] = dta;
    __syncthreads();
    for (int s = 128; s > 0; s >>= 1) {
        if (tid < s) { s_ssq[tid] += s_ssq[tid + s]; s_dta[tid] += s_dta[tid + s]; }
        __syncthreads();
    }
    if (tid == 0) {
        // q = colsum/||colsum|| (the 1/B mean factor cancels in normalization)
        double dq = s_dta[0] / sqrt(s_ssq[0]);
        double aug = 0.0;
        for (int i = 0; i < M_AUG_C; ++i) aug += 0.5 * (double)a[D_DIM + i];
        double h = floor((dq + aug) / RBIN);
        double m = fmod(h, (double)TBL);
        if (m < 0.0) m += (double)TBL;
        *qBucket = (int)m;
    }
}

// ---- Kernel D: row buckets, compare to query bucket, compact active list ----
__global__ void mask_kernel(const double* __restrict__ rowSumSq,
                            const double* __restrict__ rowDotA,
                            const double* __restrict__ maxSS,
                            const int* __restrict__ qBucket,
                            const float* __restrict__ a,
                            int* __restrict__ count,
                            int* __restrict__ list) {
    int n = blockIdx.x * 256 + threadIdx.x;
    double s  = USC / sqrt(*maxSS);
    double n2 = s * s * rowSumSq[n];
    double acc = s * rowDotA[n];
    double p = n2;
#pragma unroll
    for (int i = 0; i < M_AUG_C; ++i) {    // powers n2^(2^i), successive squaring
        acc += p * (double)a[D_DIM + i];
        p = p * p;
    }
    double h = floor(acc / RBIN);
    double m = fmod(h, (double)TBL);
    if (m < 0.0) m += (double)TBL;
    if ((int)m == *qBucket) {
        int pos = atomicAdd(count, 1);
        list[pos] = n;
    }
}

// ---- Kernel F: compacted bf16 MFMA GEMM over active rows ----
// Block tile: 128 (B rows) x 64 (active cols), BK=64. 256 threads = 4 waves,
// each wave computes 32x64 via 2x4 mfma_f32_16x16x32_bf16 frags.
// LDS stride 80 shorts (160 B): keeps ds_read_b128 16B-aligned, banks uniform.
__launch_bounds__(256, 2)
__global__ void gemm_kernel(const float* __restrict__ x,
                            const float* __restrict__ W,
                            const int* __restrict__ count,
                            const int* __restrict__ list,
                            float* __restrict__ out) {
    int cnt = *count;
    int jBase = blockIdx.y * 64;
    if (jBase >= cnt) return;          // uniform early-exit (before any barrier)
    int bRow0 = blockIdx.x * 128;

    __shared__ short xT[128 * 80];
    __shared__ short wT[64 * 80];

    int tid  = threadIdx.x;
    int wave = tid >> 6, lane = tid & 63;
    int quad = lane >> 4, l16 = lane & 15;

    // W rows this thread stages (clamped: extra cols computed but never stored)
    int wrow_ids[4];
#pragma unroll
    for (int i = 0; i < 4; ++i) {
        int idx = tid + i * 256;
        int j = jBase + (idx >> 4);
        wrow_ids[i] = list[j < cnt ? j : (cnt - 1)];
    }

    f32x4 acc[2][4];
#pragma unroll
    for (int mi = 0; mi < 2; ++mi)
#pragma unroll
        for (int nf = 0; nf < 4; ++nf)
            acc[mi][nf] = (f32x4){0.f, 0.f, 0.f, 0.f};

    for (int k0 = 0; k0 < D_DIM; k0 += 64) {
        __syncthreads();               // protect LDS from prior-iter readers
        // stage x tile: 128x64 f32 -> bf16
#pragma unroll
        for (int i = 0; i < 8; ++i) {
            int idx = tid + i * 256;
            int r = idx >> 4, kq = idx & 15;
            float4 v = *(const float4*)(x + (size_t)(bRow0 + r) * D_DIM + k0 + kq * 4);
            ushort4 b;
            b.x = f2bf(v.x); b.y = f2bf(v.y); b.z = f2bf(v.z); b.w = f2bf(v.w);
            *(ushort4*)(&xT[r * 80 + kq * 4]) = b;
        }
        // stage W tile: 64x64 f32 -> bf16 (gathered rows)
#pragma unroll
        for (int i = 0; i < 4; ++i) {
            int idx = tid + i * 256;
            int r = idx >> 4, kq = idx & 15;
            float4 v = *(const float4*)(W + (size_t)wrow_ids[i] * D_DIM + k0 + kq * 4);
            ushort4 b;
            b.x = f2bf(v.x); b.y = f2bf(v.y); b.z = f2bf(v.z); b.w = f2bf(v.w);
            *(ushort4*)(&wT[r * 80 + kq * 4]) = b;
        }
        __syncthreads();
#pragma unroll
        for (int kk = 0; kk < 64; kk += 32) {
            bf16x8 a0 = *(const bf16x8*)(&xT[(wave * 32 + l16) * 80 + kk + quad * 8]);
            bf16x8 a1 = *(const bf16x8*)(&xT[(wave * 32 + 16 + l16) * 80 + kk + quad * 8]);
#pragma unroll
            for (int nf = 0; nf < 4; ++nf) {
                bf16x8 bv = *(const bf16x8*)(&wT[(nf * 16 + l16) * 80 + kk + quad * 8]);
                acc[0][nf] = __builtin_amdgcn_mfma_f32_16x16x32_bf16(a0, bv, acc[0][nf], 0, 0, 0);
                acc[1][nf] = __builtin_amdgcn_mfma_f32_16x16x32_bf16(a1, bv, acc[1][nf], 0, 0, 0);
            }
        }
    }

    // epilogue: C/D layout col=lane&15 (B-row), row=quad*4+reg (A-row)
#pragma unroll
    for (int nf = 0; nf < 4; ++nf) {
        int j = jBase + nf * 16 + l16;
        if (j < cnt) {
            int col = list[j];
#pragma unroll
            for (int mi = 0; mi < 2; ++mi) {
                int rbase = bRow0 + wave * 32 + mi * 16 + quad * 4;
#pragma unroll
                for (int r = 0; r < 4; ++r)
                    out[(size_t)(rbase + r) * N_ROWS + col] = acc[mi][nf][r];
            }
        }
    }
}

extern "C" void kernel_launch(void* const* d_in, const int* in_sizes, int n_in,
                              void* d_out, int out_size, void* d_ws, size_t ws_size,
                              hipStream_t stream) {
    const float* x = (const float*)d_in[0];
    const float* W = (const float*)d_in[1];
    const float* a = (const float*)d_in[2];
    float* out = (float*)d_out;
    char* ws = (char*)d_ws;

    double* rowSumSq = (double*)(ws + WS_ROWSUMSQ);
    double* rowDotA  = (double*)(ws + WS_ROWDOTA);
    double* partial  = (double*)(ws + WS_PARTIAL);
    double* maxSS    = (double*)(ws + WS_MAXSS);
    int*    qBucket  = (int*)(ws + WS_QBUCKET);
    int*    count    = (int*)(ws + WS_COUNT);
    int*    list     = (int*)(ws + WS_LIST);

    hipMemsetAsync(count, 0, sizeof(int), stream);

    rowstats_kernel<<<N_ROWS / 4, 256, 0, stream>>>(W, a, rowSumSq, rowDotA);
    maxred_kernel<<<1, 1024, 0, stream>>>(rowSumSq, maxSS);
    colsum_kernel<<<dim3(D_DIM / 256, 16), 256, 0, stream>>>(x, partial);
    qhash_kernel<<<1, 256, 0, stream>>>(partial, a, qBucket);
    mask_kernel<<<N_ROWS / 256, 256, 0, stream>>>(rowSumSq, rowDotA, maxSS, qBucket,
                                                  a, count, list);

    hipMemsetAsync(out, 0, (size_t)out_size * sizeof(float), stream);
    // grid.y covers worst-case all-N active; inactive tiles exit immediately
    gemm_kernel<<<dim3(B_ROWS / 128, N_ROWS / 64), 256, 0, stream>>>(x, W, count, list, out);
}

// Round 2
// 859.561 us; speedup vs baseline: 1.2285x; 1.2285x over previous
//
#include <hip/hip_runtime.h>

// ALSH masked linear: out[B,N] = x @ (W * mask)^T, mask from bucket match.
// B=2048, D=2048, N=32768, M_AUG=5, TABLE=64, R=4.0, U=0.83.
// Measured (R1): mask is ~all-N -> treat as dense GEMM. Path A converts
// W*mask and x to bf16 once in ws, then runs m97-style global_load_lds GEMM.
// Path B (small ws) = R1's passing compacted-list kernel.

#define D_DIM 2048
#define N_ROWS 32768
#define B_ROWS 2048
#define M_AUG_C 5
#define TBL 64
#define RBIN 4.0
#define USC 0.83

typedef short bf16x8 __attribute__((ext_vector_type(8)));
typedef float f32x4 __attribute__((ext_vector_type(4)));

// ---- workspace layout (bytes) ----
#define WS_ROWSUMSQ 0                       // double[N]      256 KB
#define WS_ROWDOTA  262144                  // double[N]      256 KB
#define WS_PARTIAL  524288                  // double[16*D]   256 KB
#define WS_MAXSS    786432                  // double
#define WS_QBUCKET  786440                  // int
#define WS_COUNT    786444                  // int
#define WS_LIST     786448                  // int[N]         128 KB
#define WS_MASKF    917520                  // float[N]       128 KB
#define WS_FLAGS    1048592                 // int[256]       1 KB
#define WS_XB       1114112                 // bf16[B*D]      8 MB
#define WS_WB       9502720                 // bf16[N*D]      128 MB
#define WS_A_NEED   143720448ull            // end of WB

__device__ __forceinline__ unsigned short f2bf(float f) {
    unsigned int u = __builtin_bit_cast(unsigned int, f);
    u += 0x7fffu + ((u >> 16) & 1u);   // round-to-nearest-even
    return (unsigned short)(u >> 16);
}

typedef const __attribute__((address_space(1))) unsigned int* as1_u32p;
typedef __attribute__((address_space(3))) unsigned int* as3_u32p;

__device__ __forceinline__ void gload16(const unsigned short* g, unsigned short* l) {
    __builtin_amdgcn_global_load_lds((as1_u32p)(const void*)g, (as3_u32p)(void*)l,
                                     16, 0, 0);
}

// ---- Kernel A: per-row sum(W^2) and dot(W_row, a[:D]), fp64. One wave/row. ----
__global__ void rowstats_kernel(const float* __restrict__ W,
                                const float* __restrict__ a,
                                double* __restrict__ rowSumSq,
                                double* __restrict__ rowDotA) {
    int wave = threadIdx.x >> 6;
    int lane = threadIdx.x & 63;
    int row  = blockIdx.x * 4 + wave;
    const float* wr = W + (size_t)row * D_DIM;
    double ss = 0.0, da = 0.0;
#pragma unroll
    for (int c = 0; c < 8; ++c) {
        int off = c * 256 + lane * 4;
        float4 v  = *(const float4*)(wr + off);
        float4 av = *(const float4*)(a + off);
        ss += (double)v.x * v.x + (double)v.y * v.y + (double)v.z * v.z + (double)v.w * v.w;
        da += (double)v.x * av.x + (double)v.y * av.y + (double)v.z * av.z + (double)v.w * av.w;
    }
    for (int off = 32; off > 0; off >>= 1) {
        ss += __shfl_down(ss, off);
        da += __shfl_down(da, off);
    }
    if (lane == 0) { rowSumSq[row] = ss; rowDotA[row] = da; }
}

// ---- Kernel B: max over rowSumSq ----
__global__ void maxred_kernel(const double* __restrict__ rowSumSq,
                              double* __restrict__ maxOut) {
    __shared__ double sm[1024];
    double m = 0.0;
    for (int i = threadIdx.x; i < N_ROWS; i += 1024) m = fmax(m, rowSumSq[i]);
    sm[threadIdx.x] = m;
    __syncthreads();
    for (int s = 512; s > 0; s >>= 1) {
        if (threadIdx.x < s) sm[threadIdx.x] = fmax(sm[threadIdx.x], sm[threadIdx.x + s]);
        __syncthreads();
    }
    if (threadIdx.x == 0) *maxOut = sm[0];
}

// ---- Kernel C1: partial column sums of x ----
__global__ void colsum_kernel(const float* __restrict__ x,
                              double* __restrict__ partial) {
    int col   = blockIdx.x * 256 + threadIdx.x;
    int chunk = blockIdx.y;
    const float* xp = x + (size_t)chunk * 128 * D_DIM + col;
    double s = 0.0;
#pragma unroll 8
    for (int b = 0; b < 128; ++b) s += (double)xp[(size_t)b * D_DIM];
    partial[(size_t)chunk * D_DIM + col] = s;
}

// ---- Kernel C2: finish column sums, compute query bucket ----
__global__ void qhash_kernel(const double* __restrict__ partial,
                             const float* __restrict__ a,
                             int* __restrict__ qBucket) {
    __shared__ double s_ssq[256], s_dta[256];
    int tid = threadIdx.x;
    double ssq = 0.0, dta = 0.0;
    for (int c = tid; c < D_DIM; c += 256) {
        double cs = 0.0;
#pragma unroll
        for (int k = 0; k < 16; ++k) cs += partial[(size_t)k * D_DIM + c];
        ssq += cs * cs;
        dta += cs * (double)a[c];
    }
    s_ssq[tid] = ssq; s_dta[tid] = dta;
    __syncthreads();
    for (int s = 128; s > 0; s >>= 1) {
        if (tid < s) { s_ssq[tid] += s_ssq[tid + s]; s_dta[tid] += s_dta[tid + s]; }
        __syncthreads();
    }
    if (tid == 0) {
        double dq = s_dta[0] / sqrt(s_ssq[0]);
        double aug = 0.0;
        for (int i = 0; i < M_AUG_C; ++i) aug += 0.5 * (double)a[D_DIM + i];
        double h = floor((dq + aug) / RBIN);
        double m = fmod(h, (double)TBL);
        if (m < 0.0) m += (double)TBL;
        *qBucket = (int)m;
    }
}

// ---- Kernel D: row buckets vs query; emit mask float, tile flags, compact list ----
__global__ void mask_kernel(const double* __restrict__ rowSumSq,
                            const double* __restrict__ rowDotA,
                            const double* __restrict__ maxSS,
                            const int* __restrict__ qBucket,
                            const float* __restrict__ a,
                            int* __restrict__ count,
                            int* __restrict__ list,
                            float* __restrict__ maskF,
                            int* __restrict__ flags) {
    int n = blockIdx.x * 256 + threadIdx.x;
    double s  = USC / sqrt(*maxSS);
    double n2 = s * s * rowSumSq[n];
    double acc = s * rowDotA[n];
    double p = n2;
#pragma unroll
    for (int i = 0; i < M_AUG_C; ++i) {    // powers n2^(2^i), successive squaring
        acc += p * (double)a[D_DIM + i];
        p = p * p;
    }
    double h = floor(acc / RBIN);
    double m = fmod(h, (double)TBL);
    if (m < 0.0) m += (double)TBL;
    bool active = ((int)m == *qBucket);
    maskF[n] = active ? 1.f : 0.f;
    if (active) {
        int pos = atomicAdd(count, 1);
        list[pos] = n;
        atomicOr(&flags[n >> 7], 1);
    }
}

// ---- Kernel E1: W*mask -> bf16 (one thread per 8 elements) ----
__global__ void convw_kernel(const float* __restrict__ W,
                             const float* __restrict__ maskF,
                             unsigned short* __restrict__ wb) {
    size_t e = ((size_t)blockIdx.x * 256 + threadIdx.x) * 8;
    int row = (int)(e >> 11);
    float m = maskF[row];
    float4 v0 = *(const float4*)(W + e);
    float4 v1 = *(const float4*)(W + e + 4);
    ushort4 p0, p1;
    p0.x = f2bf(v0.x * m); p0.y = f2bf(v0.y * m);
    p0.z = f2bf(v0.z * m); p0.w = f2bf(v0.w * m);
    p1.x = f2bf(v1.x * m); p1.y = f2bf(v1.y * m);
    p1.z = f2bf(v1.z * m); p1.w = f2bf(v1.w * m);
    *(ushort4*)(wb + e)     = p0;
    *(ushort4*)(wb + e + 4) = p1;
}

// ---- Kernel E2: x -> bf16 ----
__global__ void convx_kernel(const float* __restrict__ x,
                             unsigned short* __restrict__ xb) {
    size_t e = ((size_t)blockIdx.x * 256 + threadIdx.x) * 8;
    float4 v0 = *(const float4*)(x + e);
    float4 v1 = *(const float4*)(x + e + 4);
    ushort4 p0, p1;
    p0.x = f2bf(v0.x); p0.y = f2bf(v0.y); p0.z = f2bf(v0.z); p0.w = f2bf(v0.w);
    p1.x = f2bf(v1.x); p1.y = f2bf(v1.y); p1.z = f2bf(v1.z); p1.w = f2bf(v1.w);
    *(ushort4*)(xb + e)     = p0;
    *(ushort4*)(xb + e + 4) = p1;
}

// ---- Kernel F-A: dense bf16 GEMM, m97 structure ----
// 128x128 tile, BK=64, 4 waves each computing 64x64 via 4x4 16x16x32 frags.
// LDS stride = 64 shorts (128 B) — REQUIRED unpadded for global_load_lds.
// Inactive 128-row W tiles: store zeros, skip K-loop (also replaces memset).
__launch_bounds__(256, 2)
__global__ void gemm_dense(const unsigned short* __restrict__ xb,
                           const unsigned short* __restrict__ wb,
                           const int* __restrict__ flags,
                           float* __restrict__ out) {
    int bRow0 = blockIdx.x * 128;
    int nRow0 = blockIdx.y * 128;
    int tid = threadIdx.x;

    if (flags[blockIdx.y] == 0) {
#pragma unroll
        for (int i = 0; i < 16; ++i) {
            int idx = tid + i * 256;
            int r = idx >> 5, c = idx & 31;
            *(float4*)(out + (size_t)(bRow0 + r) * N_ROWS + nRow0 + c * 4) =
                float4{0.f, 0.f, 0.f, 0.f};
        }
        return;
    }

    __shared__ __align__(16) unsigned short xT[128 * 64];
    __shared__ __align__(16) unsigned short wT[128 * 64];

    int wave = tid >> 6, lane = tid & 63;
    int quad = lane >> 4, l16 = lane & 15;
    int wr = (wave >> 1) * 64, wc = (wave & 1) * 64;

    // staging: inst t = wave*4+i covers rows [t*8, t*8+8), lane -> row t*8+l/8, col (l&7)*8
    int srow = wave * 32 + (lane >> 3);
    int scol = (lane & 7) * 8;
    const unsigned short* xg = xb + (size_t)(bRow0 + srow) * D_DIM + scol;
    const unsigned short* wg = wb + (size_t)(nRow0 + srow) * D_DIM + scol;

    f32x4 acc[4][4];
#pragma unroll
    for (int mi = 0; mi < 4; ++mi)
#pragma unroll
        for (int nf = 0; nf < 4; ++nf)
            acc[mi][nf] = (f32x4){0.f, 0.f, 0.f, 0.f};

    for (int k0 = 0; k0 < D_DIM; k0 += 64) {
        __syncthreads();               // prior-iter LDS readers done
#pragma unroll
        for (int i = 0; i < 4; ++i) {
            gload16(xg + (size_t)i * 8 * D_DIM + k0, &xT[(wave * 4 + i) * 512]);
            gload16(wg + (size_t)i * 8 * D_DIM + k0, &wT[(wave * 4 + i) * 512]);
        }
        __syncthreads();               // compiler drains vmcnt before barrier
#pragma unroll
        for (int kk = 0; kk < 64; kk += 32) {
            bf16x8 af[4], bfr[4];
#pragma unroll
            for (int mi = 0; mi < 4; ++mi)
                af[mi] = *(const bf16x8*)&xT[(wr + mi * 16 + l16) * 64 + kk + quad * 8];
#pragma unroll
            for (int nf = 0; nf < 4; ++nf)
                bfr[nf] = *(const bf16x8*)&wT[(wc + nf * 16 + l16) * 64 + kk + quad * 8];
#pragma unroll
            for (int mi = 0; mi < 4; ++mi)
#pragma unroll
                for (int nf = 0; nf < 4; ++nf)
                    acc[mi][nf] = __builtin_amdgcn_mfma_f32_16x16x32_bf16(
                        af[mi], bfr[nf], acc[mi][nf], 0, 0, 0);
        }
    }

    // epilogue: C/D layout col=lane&15 (n), row=quad*4+reg (b)
#pragma unroll
    for (int mi = 0; mi < 4; ++mi) {
        int rbase = bRow0 + wr + mi * 16 + quad * 4;
#pragma unroll
        for (int nf = 0; nf < 4; ++nf) {
            int col = nRow0 + wc + nf * 16 + l16;
#pragma unroll
            for (int r = 0; r < 4; ++r)
                out[(size_t)(rbase + r) * N_ROWS + col] = acc[mi][nf][r];
        }
    }
}

// ---- Kernel F-B (fallback, small ws): compacted-list GEMM from R1 ----
__launch_bounds__(256, 2)
__global__ void gemm_kernel(const float* __restrict__ x,
                            const float* __restrict__ W,
                            const int* __restrict__ count,
                            const int* __restrict__ list,
                            float* __restrict__ out) {
    int cnt = *count;
    int jBase = blockIdx.y * 64;
    if (jBase >= cnt) return;
    int bRow0 = blockIdx.x * 128;

    __shared__ short xT[128 * 80];
    __shared__ short wT[64 * 80];

    int tid  = threadIdx.x;
    int wave = tid >> 6, lane = tid & 63;
    int quad = lane >> 4, l16 = lane & 15;

    int wrow_ids[4];
#pragma unroll
    for (int i = 0; i < 4; ++i) {
        int idx = tid + i * 256;
        int j = jBase + (idx >> 4);
        wrow_ids[i] = list[j < cnt ? j : (cnt - 1)];
    }

    f32x4 acc[2][4];
#pragma unroll
    for (int mi = 0; mi < 2; ++mi)
#pragma unroll
        for (int nf = 0; nf < 4; ++nf)
            acc[mi][nf] = (f32x4){0.f, 0.f, 0.f, 0.f};

    for (int k0 = 0; k0 < D_DIM; k0 += 64) {
        __syncthreads();
#pragma unroll
        for (int i = 0; i < 8; ++i) {
            int idx = tid + i * 256;
            int r = idx >> 4, kq = idx & 15;
            float4 v = *(const float4*)(x + (size_t)(bRow0 + r) * D_DIM + k0 + kq * 4);
            ushort4 b;
            b.x = f2bf(v.x); b.y = f2bf(v.y); b.z = f2bf(v.z); b.w = f2bf(v.w);
            *(ushort4*)(&xT[r * 80 + kq * 4]) = b;
        }
#pragma unroll
        for (int i = 0; i < 4; ++i) {
            int idx = tid + i * 256;
            int r = idx >> 4, kq = idx & 15;
            float4 v = *(const float4*)(W + (size_t)wrow_ids[i] * D_DIM + k0 + kq * 4);
            ushort4 b;
            b.x = f2bf(v.x); b.y = f2bf(v.y); b.z = f2bf(v.z); b.w = f2bf(v.w);
            *(ushort4*)(&wT[r * 80 + kq * 4]) = b;
        }
        __syncthreads();
#pragma unroll
        for (int kk = 0; kk < 64; kk += 32) {
            bf16x8 a0 = *(const bf16x8*)(&xT[(wave * 32 + l16) * 80 + kk + quad * 8]);
            bf16x8 a1 = *(const bf16x8*)(&xT[(wave * 32 + 16 + l16) * 80 + kk + quad * 8]);
#pragma unroll
            for (int nf = 0; nf < 4; ++nf) {
                bf16x8 bv = *(const bf16x8*)(&wT[(nf * 16 + l16) * 80 + kk + quad * 8]);
                acc[0][nf] = __builtin_amdgcn_mfma_f32_16x16x32_bf16(a0, bv, acc[0][nf], 0, 0, 0);
                acc[1][nf] = __builtin_amdgcn_mfma_f32_16x16x32_bf16(a1, bv, acc[1][nf], 0, 0, 0);
            }
        }
    }

#pragma unroll
    for (int nf = 0; nf < 4; ++nf) {
        int j = jBase + nf * 16 + l16;
        if (j < cnt) {
            int col = list[j];
#pragma unroll
            for (int mi = 0; mi < 2; ++mi) {
                int rbase = bRow0 + wave * 32 + mi * 16 + quad * 4;
#pragma unroll
                for (int r = 0; r < 4; ++r)
                    out[(size_t)(rbase + r) * N_ROWS + col] = acc[mi][nf][r];
            }
        }
    }
}

extern "C" void kernel_launch(void* const* d_in, const int* in_sizes, int n_in,
                              void* d_out, int out_size, void* d_ws, size_t ws_size,
                              hipStream_t stream) {
    const float* x = (const float*)d_in[0];
    const float* W = (const float*)d_in[1];
    const float* a = (const float*)d_in[2];
    float* out = (float*)d_out;
    char* ws = (char*)d_ws;

    double* rowSumSq = (double*)(ws + WS_ROWSUMSQ);
    double* rowDotA  = (double*)(ws + WS_ROWDOTA);
    double* partial  = (double*)(ws + WS_PARTIAL);
    double* maxSS    = (double*)(ws + WS_MAXSS);
    int*    qBucket  = (int*)(ws + WS_QBUCKET);
    int*    count    = (int*)(ws + WS_COUNT);
    int*    list     = (int*)(ws + WS_LIST);
    float*  maskF    = (float*)(ws + WS_MASKF);
    int*    flags    = (int*)(ws + WS_FLAGS);
    unsigned short* xb = (unsigned short*)(ws + WS_XB);
    unsigned short* wb = (unsigned short*)(ws + WS_WB);

    hipMemsetAsync(count, 0, sizeof(int), stream);
    hipMemsetAsync(flags, 0, 256 * sizeof(int), stream);

    rowstats_kernel<<<N_ROWS / 4, 256, 0, stream>>>(W, a, rowSumSq, rowDotA);
    maxred_kernel<<<1, 1024, 0, stream>>>(rowSumSq, maxSS);
    colsum_kernel<<<dim3(D_DIM / 256, 16), 256, 0, stream>>>(x, partial);
    qhash_kernel<<<1, 256, 0, stream>>>(partial, a, qBucket);
    mask_kernel<<<N_ROWS / 256, 256, 0, stream>>>(rowSumSq, rowDotA, maxSS, qBucket,
                                                  a, count, list, maskF, flags);

    if (ws_size >= WS_A_NEED) {
        // Path A: convert once (mask folded into wb), dense m97-style GEMM.
        convw_kernel<<<(N_ROWS * (D_DIM / 8)) / 256, 256, 0, stream>>>(W, maskF, wb);
        convx_kernel<<<(B_ROWS * (D_DIM / 8)) / 256, 256, 0, stream>>>(x, xb);
        gemm_dense<<<dim3(B_ROWS / 128, N_ROWS / 128), 256, 0, stream>>>(xb, wb, flags, out);
    } else {
        // Path B: R1 fallback (fused-conversion compacted GEMM).
        hipMemsetAsync(out, 0, (size_t)out_size * sizeof(float), stream);
        gemm_kernel<<<dim3(B_ROWS / 128, N_ROWS / 64), 256, 0, stream>>>(x, W, count, list, out);
    }
}